// Round 1
// baseline (1035.772 us; speedup 1.0000x reference)
//
#include <hip/hip_runtime.h>

// ResidualConvLSTM2D on MI355X (gfx950).
// Fused per-timestep implicit GEMM: z = conv3x3([x_t || h_{t-1}], [Wx || Wh]) via
// bf16 MFMA (16x16x32), fp32 LSTM cell, fp32 residual 1x1 conv.
//
// R4: occupancy fix. R3 ran grid=256 on 256 CUs -> 1 block/CU, 1 wave/SIMD,
// OccupancyPercent 9.4%, all pipes idle (MfmaUtil 5.5%) — pure latency bound.
// Changes:
//  - M-tile 64 -> 32 pixels (2 rows x 16 cols), all 4 gates kept per block
//    (cell combine needs i,f,c,o of a pixel). Grid 256 -> 512.
//  - acc[2][4] (32 VGPR), __launch_bounds__(256,3) -> VGPR cap 168,
//    3 waves/SIMD eligible.
//  - weight tile pad 40 -> 36 shorts/row (72B stride: 18*l mod 32 distinct for
//    16 lanes -> conflict-free ds_read_b128; saves 4KB).
//  - LDS 77.8KB -> 50.6KB: patch 4x18x104 (14976) + 2 x 256x36 bf16 (18432).
//    3 blocks/CU by LDS (3*51840 = 155520 <= 163840).
//  - weight DMA: 18 chunks of 1KB round-robined across waves (wave-uniform
//    LDS dst + lane*16 src, width 16).
//  - bijective XCD swizzle (512 % 8 == 0): consecutive bids per XCD share
//    halo rows in that XCD's L2.
//  - epilogue remapped to 8ch/thread: out/c stores are 2 adjacent float4 per
//    lane (32B contiguous), 8 lanes cover a full 256B pixel line.
//
// ws layout (<4.76 MB of ~8 MB):
//   [0, 497664)          WT staged bf16 [27][256][36]
//   [557056, +2MB)       h ping  bf16 [4][64][64][64]
//   [2654208, +2MB)      h pong  bf16
// Cell state c (fp32) lives inside d_out: c_t at out[b][t][...] (read before
// that address is overwritten with the output), c_{t+1} into slab t+1.
#define B_ 4
#define T_ 16
#define H_ 64
#define W_ 64
#define CIN 32
#define F_ 64
#define NCH 256
#define KSTEPS 27
#define WSTEP 9216            // shorts per K-step weight image (256*36)
#define TSLAB (H_ * W_ * F_)  // floats between (b,t) and (b,t+1)

#define OFF_H0 557056
#define OFF_H1 2654208

typedef __attribute__((ext_vector_type(8))) short short8;
typedef __attribute__((ext_vector_type(4))) float floatx4;
typedef __attribute__((address_space(3))) unsigned int  lds_u32;
typedef __attribute__((address_space(1))) const unsigned int g_u32;

__device__ __forceinline__ unsigned short f2bf(float f) {
  union { float f; unsigned u; } v; v.f = f;
  unsigned r = v.u + 0x7FFFu + ((v.u >> 16) & 1u);   // round-to-nearest-even
  return (unsigned short)(r >> 16);
}

// tanh via hardware exp2: tanh(z) = 1 - 2/(exp(2z)+1). rcp approx (~1 ulp) is
// far inside the 4e-2 abs threshold. Saturates correctly for |z| large.
__device__ __forceinline__ float tanh_fast(float z) {
  float e = __expf(2.0f * z);
  return 1.0f - 2.0f * __builtin_amdgcn_rcpf(e + 1.0f);
}

// Staging image: WT[s][n][c], c in [0,36); c<32 -> weight for k = s*32+c of
// output channel n (k = tap*96 + ch; ch<32 from Wx else Wh); c>=32 -> 0 (pad).
__global__ void prep_weights(const float* __restrict__ Wx, const float* __restrict__ Wh,
                             unsigned short* __restrict__ WT) {
  int idx = blockIdx.x * 256 + threadIdx.x;            // 0..248831
  int s = idx / WSTEP;
  int r = idx - s * WSTEP;
  int n = r / 36;
  int c = r - n * 36;
  unsigned short v = 0;
  if (c < 32) {
    int k  = s * 32 + c;
    int g  = k / 96;
    int ch = k - g * 96;
    float f = (ch < CIN) ? Wx[(g * CIN + ch) * NCH + n]
                         : Wh[(g * F_ + (ch - CIN)) * NCH + n];
    v = f2bf(f);
  }
  WT[idx] = v;
}

// Zero h ping+pong (4 MB in ws).
__global__ void prep_zero_h(float4* __restrict__ p) {
  int idx = blockIdx.x * 256 + threadIdx.x;
  p[idx] = make_float4(0.f, 0.f, 0.f, 0.f);
}

// Zero c0 = out slabs [b][0][...].
__global__ void prep_zero_c(float* __restrict__ out) {
  int idx = blockIdx.x * 256 + threadIdx.x;            // float4 units
  int b = idx >> 16;
  int i = idx & 65535;
  ((float4*)(out + (size_t)b * (T_ * TSLAB)))[i] = make_float4(0.f, 0.f, 0.f, 0.f);
}

// Stage one K-step's weight tile (256 rows x 72 B = 18432 B) as 18 x 1KB
// chunks round-robined across the 4 waves. LDS dst is wave-uniform + lane*16.
__device__ __forceinline__ void stage_wt(const unsigned short* __restrict__ src,
                                         short* dstbuf, int w, int lane) {
  __attribute__((address_space(3))) unsigned short* d =
      (__attribute__((address_space(3))) unsigned short*)dstbuf;
  const unsigned short* s = src + lane * 8;
  #pragma unroll
  for (int i = 0; i < 4; i++) {
    int q = w + 4 * i;                    // w..w+12, always < 18
    __builtin_amdgcn_global_load_lds((g_u32*)(s + q * 512), (lds_u32*)(d + q * 512),
                                     16, 0, 0);
  }
  if (w < 2) {                            // chunks 16, 17 (wave-uniform branch)
    int q = w + 16;
    __builtin_amdgcn_global_load_lds((g_u32*)(s + q * 512), (lds_u32*)(d + q * 512),
                                     16, 0, 0);
  }
}

__global__ __launch_bounds__(256, 3)
void step_kernel(const float* __restrict__ x, const float* __restrict__ bias,
                 const float* __restrict__ Wp, const float* __restrict__ bp,
                 const unsigned short* __restrict__ WT,
                 const unsigned short* __restrict__ hprev,
                 unsigned short* __restrict__ hnew,
                 float* __restrict__ out, int t)
{
  // LDS: patch [4][18][104] sh (14976) | bl0 [256][36] sh (18432) | bl1 (18432)
  // epilogue reuse: gact [4*32][68] fp32 (34816 B) at 0, WpL 8 KB at 34816.
  __shared__ __align__(16) char smem[51840];
  short* patch = (short*)smem;
  short* bl0   = (short*)(smem + 14976);
  short* bl1   = (short*)(smem + 33408);
  float* gact  = (float*)smem;
  float* WpL   = (float*)(smem + 34816);

  const int tid  = threadIdx.x;
  const int w    = tid >> 6;
  const int lane = tid & 63;
  const int quad = lane >> 4;
  const int lr   = lane & 15;

  // bijective XCD swizzle: 512 blocks, 8 XCDs, 64 consecutive bids per XCD.
  const int raw = blockIdx.x;
  const int bid = (raw & 7) * 64 + (raw >> 3);
  const int b   = bid >> 7;
  const int rem = bid & 127;
  const int y0  = (rem >> 2) << 1;   // 2-row tile
  const int x0  = (rem & 3) << 4;    // 16-col tile

  // ---- prefetch K-step 0 weights into bl0 (DMA in flight during patch staging)
  stage_wt(WT, bl0, w, lane);

  // ---- stage input patch: 4 rows x 18 cols x 96 ch (x bf16 | h bf16),
  // split per entry into x-half / h-half across 144 threads.
  if (tid < 144) {
    int e = tid >> 1, half = tid & 1;
    int sy = e / 18, sx = e - sy * 18;
    int yy = y0 + sy - 1, xx = x0 + sx - 1;
    short* dst = patch + e * 104;
    bool in = (yy >= 0 && yy < H_ && xx >= 0 && xx < W_);
    if (half == 0) {                      // x channels 0..31 -> bf16
      if (in) {
        const float4* xs = (const float4*)(x + ((((b * T_ + t) * H_ + yy) * W_ + xx) * CIN));
        #pragma unroll
        for (int j = 0; j < 4; j++) {
          float4 f0 = xs[2 * j];
          float4 f1 = xs[2 * j + 1];
          union { short8 v; unsigned short u[8]; } pk;
          pk.u[0] = f2bf(f0.x); pk.u[1] = f2bf(f0.y); pk.u[2] = f2bf(f0.z); pk.u[3] = f2bf(f0.w);
          pk.u[4] = f2bf(f1.x); pk.u[5] = f2bf(f1.y); pk.u[6] = f2bf(f1.z); pk.u[7] = f2bf(f1.w);
          ((short8*)dst)[j] = pk.v;
        }
      } else {
        uint4 z = make_uint4(0, 0, 0, 0);
        uint4* d4 = (uint4*)dst;
        #pragma unroll
        for (int j = 0; j < 4; j++) d4[j] = z;
      }
    } else {                              // h channels (already bf16)
      uint4* d2 = (uint4*)(dst + 32);
      if (in) {
        const uint4* hs = (const uint4*)(hprev + ((b * H_ + yy) * W_ + xx) * F_);
        #pragma unroll
        for (int j = 0; j < 8; j++) d2[j] = hs[j];
      } else {
        uint4 z = make_uint4(0, 0, 0, 0);
        #pragma unroll
        for (int j = 0; j < 8; j++) d2[j] = z;
      }
    }
  }

  float bias_r[4];
  #pragma unroll
  for (int nf = 0; nf < 4; nf++) bias_r[nf] = bias[w * 64 + nf * 16 + lr];

  floatx4 acc[2][4];
  #pragma unroll
  for (int mf = 0; mf < 2; mf++)
    #pragma unroll
    for (int nf = 0; nf < 4; nf++)
      acc[mf][nf] = (floatx4){0.f, 0.f, 0.f, 0.f};

  __syncthreads();   // patch staged + bl0 DMA drained (vmcnt(0) before barrier)

  // ---- K loop: 27 steps of BK=32 over K=864; double-buffered weight tile,
  //      ONE barrier per step; prefetch s+1 during compute of s.
  const unsigned short* wsrc = WT + WSTEP;   // staging image for s+1
  for (int s = 0; s < KSTEPS; s++) {
    short* cur = (s & 1) ? bl1 : bl0;
    if (s < KSTEPS - 1) {
      stage_wt(wsrc, (s & 1) ? bl0 : bl1, w, lane);
      wsrc += WSTEP;
    }
    int g  = s / 3;
    int c0 = (s - g * 3) * 32;
    int dy = g / 3, dx = g - dy * 3;
    short8 afr[2], bfr[4];
    #pragma unroll
    for (int mf = 0; mf < 2; mf++)          // pixel = mf*16 + lr (row mf, col lr)
      afr[mf] = *(const short8*)(patch + ((mf + dy) * 18 + lr + dx) * 104 + c0 + quad * 8);
    #pragma unroll
    for (int nf = 0; nf < 4; nf++)          // wave w owns gate w
      bfr[nf] = *(const short8*)(cur + (w * 64 + nf * 16 + lr) * 36 + quad * 8);
    #pragma unroll
    for (int mf = 0; mf < 2; mf++)
      #pragma unroll
      for (int nf = 0; nf < 4; nf++)
        acc[mf][nf] = __builtin_amdgcn_mfma_f32_16x16x32_bf16(afr[mf], bfr[nf], acc[mf][nf], 0, 0, 0);
    __syncthreads();   // everyone done with cur; prefetch DMA drained for next iter
  }

  // ---- epilogue phase 1: activations -> gact[(gate*32+m)*68 + ch], WpL
  #pragma unroll
  for (int mf = 0; mf < 2; mf++)
    #pragma unroll
    for (int nf = 0; nf < 4; nf++)
      #pragma unroll
      for (int r = 0; r < 4; r++) {
        int mm = mf * 16 + quad * 4 + r;          // D row = quad*4 + reg
        float z = acc[mf][nf][r] + bias_r[nf];
        float a;
        if (w == 2) a = tanh_fast(z);             // candidate gate
        else {                                    // hard_sigmoid for i, f, o
          a = __builtin_fmaf(z, 0.2f, 0.5f);
          a = fminf(fmaxf(a, 0.f), 1.f);
        }
        gact[(w * 32 + mm) * 68 + nf * 16 + lr] = a;
      }
  {                                               // Wp -> LDS (512 float4)
    float4* d = (float4*)WpL;
    const float4* sWp = (const float4*)Wp;
    d[tid * 2]     = sWp[tid * 2];
    d[tid * 2 + 1] = sWp[tid * 2 + 1];
  }

  const int mloc = tid >> 3;                      // pixel in tile (0..31)
  const int cb   = (tid & 7) * 8;                 // 8-channel slice
  const int tyo  = mloc >> 4, txo = mloc & 15;
  const int gy   = y0 + tyo, gx = x0 + txo;
  const int hbase   = ((b * H_ + gy) * W_ + gx) * F_ + cb;
  const int outbase = (((b * T_ + t) * H_ + gy) * W_ + gx) * F_ + cb;

  // prefetch x (residual) and c_t (global) before the barrier
  float xv[32];
  {
    const float4* xs = (const float4*)(x + ((((b * T_ + t) * H_ + gy) * W_ + gx) * CIN));
    #pragma unroll
    for (int j = 0; j < 8; j++) {
      float4 f = xs[j];
      xv[4 * j] = f.x; xv[4 * j + 1] = f.y; xv[4 * j + 2] = f.z; xv[4 * j + 3] = f.w;
    }
  }
  float4 co4[2];
  co4[0] = *(const float4*)(out + outbase);
  co4[1] = *(const float4*)(out + outbase + 4);

  __syncthreads();                                // gact + WpL visible

  // ---- residual 1x1 conv (fp32), 8 output channels per thread
  float res[8];
  #pragma unroll
  for (int j = 0; j < 8; j++) res[j] = bp[cb + j];
  #pragma unroll
  for (int ci = 0; ci < 32; ci++) {
    float xf = xv[ci];
    float4 w0 = *(const float4*)(WpL + ci * 64 + cb);
    float4 w1 = *(const float4*)(WpL + ci * 64 + cb + 4);
    res[0] += xf * w0.x; res[1] += xf * w0.y; res[2] += xf * w0.z; res[3] += xf * w0.w;
    res[4] += xf * w1.x; res[5] += xf * w1.y; res[6] += xf * w1.z; res[7] += xf * w1.w;
  }

  // ---- LSTM cell combine
  union { unsigned short hv[8]; uint4 q; } hu;
  #pragma unroll
  for (int j4 = 0; j4 < 2; j4++) {
    int jj = j4 * 4;
    float4 gi = *(const float4*)(gact + (0 * 32 + mloc) * 68 + cb + jj);
    float4 gf = *(const float4*)(gact + (1 * 32 + mloc) * 68 + cb + jj);
    float4 gg = *(const float4*)(gact + (2 * 32 + mloc) * 68 + cb + jj);
    float4 go = *(const float4*)(gact + (3 * 32 + mloc) * 68 + cb + jj);
    float cold[4] = {co4[j4].x, co4[j4].y, co4[j4].z, co4[j4].w};
    float iv[4] = {gi.x, gi.y, gi.z, gi.w};
    float fv[4] = {gf.x, gf.y, gf.z, gf.w};
    float gv[4] = {gg.x, gg.y, gg.z, gg.w};
    float ov[4] = {go.x, go.y, go.z, go.w};
    float cn4[4], h4[4];
    #pragma unroll
    for (int e = 0; e < 4; e++) {
      float cn = fv[e] * cold[e] + iv[e] * gv[e];
      float h  = ov[e] * tanh_fast(cn);
      cn4[e] = cn; h4[e] = h;
      hu.hv[jj + e] = f2bf(h);
    }
    if (t < T_ - 1)                               // c_{t+1} -> next out slab
      *(float4*)(out + outbase + TSLAB + jj) = make_float4(cn4[0], cn4[1], cn4[2], cn4[3]);
    *(float4*)(out + outbase + jj) = make_float4(h4[0] + res[jj + 0], h4[1] + res[jj + 1],
                                                 h4[2] + res[jj + 2], h4[3] + res[jj + 3]);
  }
  *(uint4*)(hnew + hbase) = hu.q;
}

extern "C" void kernel_launch(void* const* d_in, const int* in_sizes, int n_in,
                              void* d_out, int out_size, void* d_ws, size_t ws_size,
                              hipStream_t stream) {
  const float* x    = (const float*)d_in[0];
  const float* Wx   = (const float*)d_in[1];
  const float* Wh   = (const float*)d_in[2];
  const float* bias = (const float*)d_in[3];
  const float* Wp   = (const float*)d_in[4];
  const float* bp   = (const float*)d_in[5];
  float* out = (float*)d_out;

  unsigned short* WT = (unsigned short*)d_ws;
  unsigned short* h0 = (unsigned short*)((char*)d_ws + OFF_H0);
  unsigned short* h1 = (unsigned short*)((char*)d_ws + OFF_H1);

  hipLaunchKernelGGL(prep_weights, dim3(972), dim3(256), 0, stream, Wx, Wh, WT);
  hipLaunchKernelGGL(prep_zero_h, dim3(1024), dim3(256), 0, stream,
                     (float4*)((char*)d_ws + OFF_H0));
  hipLaunchKernelGGL(prep_zero_c, dim3(1024), dim3(256), 0, stream, out);

  for (int t = 0; t < T_; t++) {
    const unsigned short* hp = (t & 1) ? h1 : h0;
    unsigned short*       hn = (t & 1) ? h0 : h1;
    hipLaunchKernelGGL(step_kernel, dim3(512), dim3(256), 0, stream,
                       x, bias, Wp, bp, WT, hp, hn, out, t);
  }
}

// Round 2
// 656.088 us; speedup vs baseline: 1.5787x; 1.5787x over previous
//
#include <hip/hip_runtime.h>

// ResidualConvLSTM2D on MI355X (gfx950).
// Fused per-timestep implicit GEMM: z = conv3x3([x_t || h_{t-1}], [Wx || Wh]) via
// bf16 MFMA (16x16x32), fp32 LSTM cell, fp32 residual 1x1 conv.
//
// R5: R4 regressed (710 -> 1036 us): halving the M-tile doubled total weight
// traffic (every block reads the full 497KB weight image; grid 512 -> 254MB of
// weight requests/step, hbm_bytes 75 -> 144MB, traffic-bound at 2.2TB/s).
// Fix: keep grid=256 (1 block/CU, M=64 px, N=256) so traffic stays at the R3
// level, and attack R3's real problem (1 wave/SIMD latency exposure) with
// 1024-thread blocks = 16 waves = 4 waves/SIMD:
//  - wave w -> (gate = w>>2, M-quarter = w&3): acc[1][4], 4 MFMAs/K-step.
//  - BK=64: two K-steps per barrier, 27 -> 14 barriers; 40KB weight DMA per
//    phase round-robined over 16 waves (40 x 1KB chunks), full phase to land.
//  - weight image padded to 28 K-steps (step 27 zero) so the last phase can
//    stage blindly; compute guards s < 27.
//  - LDS 110.2KB: patch 4x34x104 sh (28288) + 2 x [2][256][40] sh (40960 each).
//    1 block/CU (fits 160KB). Epilogue reuses: gact [256][68] f32 at 0,
//    WpL 8KB at 69632.
//  - XCD swizzle for grid 256 (32 consecutive bids per XCD).
//
// ws layout (<4.79 MB of ~8 MB):
//   [0, 573440)          WT staged bf16 [28][256][40] (step 27 zeroed)
//   [589824, +2MB)       h ping  bf16 [4][64][64][64]
//   [2686976, +2MB)      h pong  bf16
// Cell state c (fp32) lives inside d_out: c_t at out[b][t][...] (read before
// that address is overwritten with the output), c_{t+1} into slab t+1.
#define B_ 4
#define T_ 16
#define H_ 64
#define W_ 64
#define CIN 32
#define F_ 64
#define NCH 256
#define KSTEPS 27
#define NPHASE 14
#define WSTEP 10240           // shorts per K-step weight image [256][40]
#define PHSTEP 20480          // shorts per phase (2 K-steps)
#define TSLAB (H_ * W_ * F_)  // floats between (b,t) and (b,t+1)

#define OFF_H0 589824
#define OFF_H1 2686976

typedef __attribute__((ext_vector_type(8))) short short8;
typedef __attribute__((ext_vector_type(4))) float floatx4;
typedef __attribute__((address_space(3))) unsigned int  lds_u32;
typedef __attribute__((address_space(1))) const unsigned int g_u32;

__device__ __forceinline__ unsigned short f2bf(float f) {
  union { float f; unsigned u; } v; v.f = f;
  unsigned r = v.u + 0x7FFFu + ((v.u >> 16) & 1u);   // round-to-nearest-even
  return (unsigned short)(r >> 16);
}

// tanh via hardware exp2: tanh(z) = 1 - 2/(exp(2z)+1). rcp approx (~1 ulp) is
// far inside the 4e-2 abs threshold. Saturates correctly for |z| large.
__device__ __forceinline__ float tanh_fast(float z) {
  float e = __expf(2.0f * z);
  return 1.0f - 2.0f * __builtin_amdgcn_rcpf(e + 1.0f);
}

// Staging image: WT[s][n][c], c in [0,40); c<32 -> weight for k = s*32+c of
// output channel n (k = tap*96 + ch; ch<32 from Wx else Wh); pad/step-27 -> 0.
__global__ void prep_weights(const float* __restrict__ Wx, const float* __restrict__ Wh,
                             unsigned short* __restrict__ WT) {
  int idx = blockIdx.x * 256 + threadIdx.x;            // 0..286719
  int s = idx / WSTEP;
  int r = idx - s * WSTEP;
  int n = r / 40;
  int c = r - n * 40;
  unsigned short v = 0;
  if (c < 32 && s < KSTEPS) {
    int k  = s * 32 + c;
    int g  = k / 96;
    int ch = k - g * 96;
    float f = (ch < CIN) ? Wx[(g * CIN + ch) * NCH + n]
                         : Wh[(g * F_ + (ch - CIN)) * NCH + n];
    v = f2bf(f);
  }
  WT[idx] = v;
}

// Zero h ping+pong (4 MB in ws).
__global__ void prep_zero_h(float4* __restrict__ p) {
  int idx = blockIdx.x * 256 + threadIdx.x;
  p[idx] = make_float4(0.f, 0.f, 0.f, 0.f);
}

// Zero c0 = out slabs [b][0][...].
__global__ void prep_zero_c(float* __restrict__ out) {
  int idx = blockIdx.x * 256 + threadIdx.x;            // float4 units
  int b = idx >> 16;
  int i = idx & 65535;
  ((float4*)(out + (size_t)b * (T_ * TSLAB)))[i] = make_float4(0.f, 0.f, 0.f, 0.f);
}

// Stage one phase's weight tile (2 K-steps, 40960 B) as 40 x 1KB chunks
// round-robined across 16 waves. LDS dst is wave-uniform + lane*16.
__device__ __forceinline__ void stage_wt2(const unsigned short* __restrict__ src,
                                          short* dstbuf, int w, int lane) {
  __attribute__((address_space(3))) unsigned short* d =
      (__attribute__((address_space(3))) unsigned short*)dstbuf;
  const unsigned short* s = src + lane * 8;
  __builtin_amdgcn_global_load_lds((g_u32*)(s + w * 512),
                                   (lds_u32*)(d + w * 512), 16, 0, 0);
  __builtin_amdgcn_global_load_lds((g_u32*)(s + (w + 16) * 512),
                                   (lds_u32*)(d + (w + 16) * 512), 16, 0, 0);
  if (w < 8)                               // chunks 32..39 (wave-uniform branch)
    __builtin_amdgcn_global_load_lds((g_u32*)(s + (w + 32) * 512),
                                     (lds_u32*)(d + (w + 32) * 512), 16, 0, 0);
}

__global__ __launch_bounds__(1024, 1)
void step_kernel(const float* __restrict__ x, const float* __restrict__ bias,
                 const float* __restrict__ Wp, const float* __restrict__ bp,
                 const unsigned short* __restrict__ WT,
                 const unsigned short* __restrict__ hprev,
                 unsigned short* __restrict__ hnew,
                 float* __restrict__ out, int t)
{
  // LDS: patch [4][34][104] sh (28288) | bl0 [2][256][40] sh (40960) | bl1.
  // epilogue reuse: gact [256][68] fp32 (69632 B) at 0, WpL 8 KB at 69632.
  __shared__ __align__(16) char smem[110208];
  short* patch = (short*)smem;
  short* bl0   = (short*)(smem + 28288);
  short* bl1   = (short*)(smem + 69248);
  float* gact  = (float*)smem;
  float* WpL   = (float*)(smem + 69632);

  const int tid  = threadIdx.x;
  const int w    = tid >> 6;               // 0..15
  const int lane = tid & 63;
  const int quad = lane >> 4;
  const int lr   = lane & 15;
  const int gate = w >> 2;                 // wave's gate (i,f,c,o)
  const int mq   = w & 3;                  // wave's M-quarter (16 pixels)

  // bijective XCD swizzle: 256 blocks, 8 XCDs, 32 consecutive bids per XCD.
  const int raw = blockIdx.x;
  const int bid = (raw & 7) * 32 + (raw >> 3);
  const int b   = bid >> 6;
  const int rem = bid & 63;
  const int y0  = (rem >> 1) << 1;   // 2-row tile
  const int x0  = (rem & 1) << 5;    // 32-col half

  // ---- prefetch phase-0 weights into bl0 (DMA in flight during patch staging)
  stage_wt2(WT, bl0, w, lane);

  // ---- stage input patch: 4 rows x 34 cols x 96 ch (x bf16 | h bf16),
  // split per entry into x-half / h-half across 272 threads.
  if (tid < 272) {
    int e = tid >> 1, half = tid & 1;
    int sy = e / 34, sx = e - sy * 34;
    int yy = y0 + sy - 1, xx = x0 + sx - 1;
    short* dst = patch + e * 104;
    bool in = (yy >= 0 && yy < H_ && xx >= 0 && xx < W_);
    if (half == 0) {                      // x channels 0..31 -> bf16
      if (in) {
        const float4* xs = (const float4*)(x + ((((b * T_ + t) * H_ + yy) * W_ + xx) * CIN));
        #pragma unroll
        for (int j = 0; j < 4; j++) {
          float4 f0 = xs[2 * j];
          float4 f1 = xs[2 * j + 1];
          union { short8 v; unsigned short u[8]; } pk;
          pk.u[0] = f2bf(f0.x); pk.u[1] = f2bf(f0.y); pk.u[2] = f2bf(f0.z); pk.u[3] = f2bf(f0.w);
          pk.u[4] = f2bf(f1.x); pk.u[5] = f2bf(f1.y); pk.u[6] = f2bf(f1.z); pk.u[7] = f2bf(f1.w);
          ((short8*)dst)[j] = pk.v;
        }
      } else {
        uint4 z = make_uint4(0, 0, 0, 0);
        uint4* d4 = (uint4*)dst;
        #pragma unroll
        for (int j = 0; j < 4; j++) d4[j] = z;
      }
    } else {                              // h channels (already bf16)
      uint4* d2 = (uint4*)(dst + 32);
      if (in) {
        const uint4* hs = (const uint4*)(hprev + ((b * H_ + yy) * W_ + xx) * F_);
        #pragma unroll
        for (int j = 0; j < 8; j++) d2[j] = hs[j];
      } else {
        uint4 z = make_uint4(0, 0, 0, 0);
        #pragma unroll
        for (int j = 0; j < 8; j++) d2[j] = z;
      }
    }
  }

  float bias_r[4];
  #pragma unroll
  for (int nf = 0; nf < 4; nf++) bias_r[nf] = bias[gate * 64 + nf * 16 + lr];

  floatx4 acc[4];
  #pragma unroll
  for (int nf = 0; nf < 4; nf++) acc[nf] = (floatx4){0.f, 0.f, 0.f, 0.f};

  // wave's A-row (pixel) for the MFMA A operand
  const int px = mq * 16 + lr;            // 0..63
  const int ty = px >> 5, tx = px & 31;

  __syncthreads();   // patch staged + bl0 DMA drained (vmcnt(0) before barrier)

  // ---- K loop: 14 phases of 2 K-steps (BK=64) over K=864; double-buffered
  //      weight tile, ONE barrier per phase; prefetch p+1 during compute of p.
  const unsigned short* wsrc = WT + PHSTEP;   // staging image for phase p+1
  for (int p = 0; p < NPHASE; p++) {
    short* cur = (p & 1) ? bl1 : bl0;
    if (p < NPHASE - 1) {
      stage_wt2(wsrc, (p & 1) ? bl0 : bl1, w, lane);
      wsrc += PHSTEP;
    }
    #pragma unroll
    for (int half = 0; half < 2; half++) {
      int s = 2 * p + half;
      if (s < KSTEPS) {
        int g  = s / 3;
        int c0 = (s - g * 3) * 32;
        int dy = g / 3, dx = g - dy * 3;
        short8 afr = *(const short8*)(patch + ((ty + dy) * 34 + tx + dx) * 104 + c0 + quad * 8);
        #pragma unroll
        for (int nf = 0; nf < 4; nf++) {
          short8 bfr = *(const short8*)(cur + half * WSTEP + (gate * 64 + nf * 16 + lr) * 40 + quad * 8);
          acc[nf] = __builtin_amdgcn_mfma_f32_16x16x32_bf16(afr, bfr, acc[nf], 0, 0, 0);
        }
      }
    }
    __syncthreads();   // everyone done with cur; prefetch DMA drained
  }

  // ---- epilogue phase 1: activations -> gact[(gate*64+px)*68 + ch], WpL
  #pragma unroll
  for (int nf = 0; nf < 4; nf++)
    #pragma unroll
    for (int r = 0; r < 4; r++) {
      int mm = quad * 4 + r;                      // D row = quad*4 + reg
      float z = acc[nf][r] + bias_r[nf];
      float a;
      if (gate == 2) a = tanh_fast(z);            // candidate gate
      else {                                      // hard_sigmoid for i, f, o
        a = __builtin_fmaf(z, 0.2f, 0.5f);
        a = fminf(fmaxf(a, 0.f), 1.f);
      }
      gact[(gate * 64 + mq * 16 + mm) * 68 + nf * 16 + lr] = a;
    }
  if (tid < 512)                                  // Wp -> LDS (512 float4)
    ((float4*)WpL)[tid] = ((const float4*)Wp)[tid];

  const int mloc = tid >> 4;                      // pixel in tile (0..63)
  const int cb   = (tid & 15) * 4;                // 4-channel slice
  const int tyo  = mloc >> 5, txo = mloc & 31;
  const int gy   = y0 + tyo, gx = x0 + txo;
  const int hbase   = ((b * H_ + gy) * W_ + gx) * F_ + cb;
  const int outbase = (((b * T_ + t) * H_ + gy) * W_ + gx) * F_ + cb;

  // prefetch x (residual) and c_t (global) before the barrier
  float xv[32];
  {
    const float4* xs = (const float4*)(x + ((((b * T_ + t) * H_ + gy) * W_ + gx) * CIN));
    #pragma unroll
    for (int j = 0; j < 8; j++) {
      float4 f = xs[j];
      xv[4 * j] = f.x; xv[4 * j + 1] = f.y; xv[4 * j + 2] = f.z; xv[4 * j + 3] = f.w;
    }
  }
  float4 co4 = *(const float4*)(out + outbase);

  __syncthreads();                                // gact + WpL visible

  // ---- residual 1x1 conv (fp32), 4 output channels per thread
  float res[4];
  #pragma unroll
  for (int j = 0; j < 4; j++) res[j] = bp[cb + j];
  #pragma unroll
  for (int ci = 0; ci < 32; ci++) {
    float xf = xv[ci];
    float4 wv = *(const float4*)(WpL + ci * 64 + cb);
    res[0] += xf * wv.x; res[1] += xf * wv.y; res[2] += xf * wv.z; res[3] += xf * wv.w;
  }

  // ---- LSTM cell combine (4 channels per thread)
  float4 gi = *(const float4*)(gact + (0 * 64 + mloc) * 68 + cb);
  float4 gf = *(const float4*)(gact + (1 * 64 + mloc) * 68 + cb);
  float4 gg = *(const float4*)(gact + (2 * 64 + mloc) * 68 + cb);
  float4 go = *(const float4*)(gact + (3 * 64 + mloc) * 68 + cb);
  float cold[4] = {co4.x, co4.y, co4.z, co4.w};
  float iv[4] = {gi.x, gi.y, gi.z, gi.w};
  float fv[4] = {gf.x, gf.y, gf.z, gf.w};
  float gv[4] = {gg.x, gg.y, gg.z, gg.w};
  float ov[4] = {go.x, go.y, go.z, go.w};
  float cn4[4], h4[4];
  union { unsigned short hv[4]; uint2 q; } hu;
  #pragma unroll
  for (int e = 0; e < 4; e++) {
    float cn = fv[e] * cold[e] + iv[e] * gv[e];
    float h  = ov[e] * tanh_fast(cn);
    cn4[e] = cn; h4[e] = h;
    hu.hv[e] = f2bf(h);
  }
  if (t < T_ - 1)                                 // c_{t+1} -> next out slab
    *(float4*)(out + outbase + TSLAB) = make_float4(cn4[0], cn4[1], cn4[2], cn4[3]);
  *(float4*)(out + outbase) = make_float4(h4[0] + res[0], h4[1] + res[1],
                                          h4[2] + res[2], h4[3] + res[3]);
  *(uint2*)(hnew + hbase) = hu.q;
}

extern "C" void kernel_launch(void* const* d_in, const int* in_sizes, int n_in,
                              void* d_out, int out_size, void* d_ws, size_t ws_size,
                              hipStream_t stream) {
  const float* x    = (const float*)d_in[0];
  const float* Wx   = (const float*)d_in[1];
  const float* Wh   = (const float*)d_in[2];
  const float* bias = (const float*)d_in[3];
  const float* Wp   = (const float*)d_in[4];
  const float* bp   = (const float*)d_in[5];
  float* out = (float*)d_out;

  unsigned short* WT = (unsigned short*)d_ws;
  unsigned short* h0 = (unsigned short*)((char*)d_ws + OFF_H0);
  unsigned short* h1 = (unsigned short*)((char*)d_ws + OFF_H1);

  hipLaunchKernelGGL(prep_weights, dim3(1120), dim3(256), 0, stream, Wx, Wh, WT);
  hipLaunchKernelGGL(prep_zero_h, dim3(1024), dim3(256), 0, stream,
                     (float4*)((char*)d_ws + OFF_H0));
  hipLaunchKernelGGL(prep_zero_c, dim3(1024), dim3(256), 0, stream, out);

  for (int t = 0; t < T_; t++) {
    const unsigned short* hp = (t & 1) ? h1 : h0;
    unsigned short*       hn = (t & 1) ? h0 : h1;
    hipLaunchKernelGGL(step_kernel, dim3(256), dim3(1024), 0, stream,
                       x, bias, Wp, bp, WT, hp, hn, out, t);
  }
}